// Round 1
// baseline (4901.810 us; speedup 1.0000x reference)
//
#include <hip/hip_runtime.h>

#define HD 64  // hidden dim

// ---------------------------------------------------------------------------
// zero-fill (float4)
// ---------------------------------------------------------------------------
__global__ void __launch_bounds__(256) zero_kernel(float4* p, long n4) {
    long i = blockIdx.x * (long)blockDim.x + threadIdx.x;
    long stride = (long)gridDim.x * blockDim.x;
    float4 z; z.x = z.y = z.z = z.w = 0.f;
    for (; i < n4; i += stride) p[i] = z;
}

// ---------------------------------------------------------------------------
// node init: h = relu([emb[z], t] @ rw1 + rb1) @ rw2 + rb2
// rw1: [65,64] row-major, rw2: [64,64]
// block = 256 threads = 4 nodes x 64 channels, weights in LDS
// ---------------------------------------------------------------------------
__global__ void __launch_bounds__(256) node_init_kernel(
    const int* __restrict__ z, const float* __restrict__ t,
    const float* __restrict__ emb,
    const float* __restrict__ rw1, const float* __restrict__ rb1,
    const float* __restrict__ rw2, const float* __restrict__ rb2,
    float* __restrict__ h, int N)
{
    __shared__ float s_w1[65 * 64];
    __shared__ float s_w2[64 * 64];
    __shared__ float s_x[4][65];
    __shared__ float s_y1[4][64];

    int tid = threadIdx.x;
    for (int i = tid; i < 65 * 64; i += 256) s_w1[i] = rw1[i];
    for (int i = tid; i < 64 * 64; i += 256) s_w2[i] = rw2[i];
    __syncthreads();

    int local = tid >> 6;   // 0..3
    int c     = tid & 63;   // channel
    float b1 = rb1[c];
    float b2 = rb2[c];

    long stride = (long)gridDim.x * 4;
    for (long base = (long)blockIdx.x * 4; base < N; base += stride) {
        long node = base + local;
        if (node < N) {
            s_x[local][c] = emb[(long)z[node] * HD + c];
            if (c == 0) s_x[local][64] = t[node];
        }
        __syncthreads();
        if (node < N) {
            float acc = b1;
            #pragma unroll
            for (int k = 0; k < 65; ++k)
                acc = fmaf(s_x[local][k], s_w1[k * 64 + c], acc);
            s_y1[local][c] = fmaxf(acc, 0.f);
        }
        __syncthreads();
        if (node < N) {
            float acc = b2;
            #pragma unroll
            for (int k = 0; k < 64; ++k)
                acc = fmaf(s_y1[local][k], s_w2[k * 64 + c], acc);
            h[node * HD + c] = acc;
        }
        __syncthreads();
    }
}

// ---------------------------------------------------------------------------
// edge scatter: agg[dst] += relu(h[src] + edge_attr)
// 16 threads per edge, float4 per thread. Consecutive 64 lanes cover 4
// complete edge rows -> fully contiguous 1KB edge_attr reads per wave.
// ---------------------------------------------------------------------------
__global__ void __launch_bounds__(256) scatter_kernel(
    const int* __restrict__ src, const int* __restrict__ dst,
    const float* __restrict__ h, const float* __restrict__ ea,
    float* __restrict__ agg, long E)
{
    long total = E * 16;
    long i = blockIdx.x * (long)blockDim.x + threadIdx.x;
    long stride = (long)gridDim.x * blockDim.x;
    for (; i < total; i += stride) {
        long e = i >> 4;
        int g = (int)(i & 15) * 4;
        int s = src[e];
        int d = dst[e];
        float4 a  = *(const float4*)(ea + e * HD + g);
        float4 hv = *(const float4*)(h + (long)s * HD + g);
        float* ap = agg + (long)d * HD + g;
        unsafeAtomicAdd(ap + 0, fmaxf(a.x + hv.x, 0.f));
        unsafeAtomicAdd(ap + 1, fmaxf(a.y + hv.y, 0.f));
        unsafeAtomicAdd(ap + 2, fmaxf(a.z + hv.z, 0.f));
        unsafeAtomicAdd(ap + 3, fmaxf(a.w + hv.w, 0.f));
    }
}

// ---------------------------------------------------------------------------
// node update: x = scat + h;  y = relu(x@w1+b1)@w2+b2;
// if relu_flag: y = relu(y);  out = y + h
// ---------------------------------------------------------------------------
__global__ void __launch_bounds__(256) node_update_kernel(
    const float* __restrict__ scat, const float* __restrict__ h,
    const float* __restrict__ w1, const float* __restrict__ b1,
    const float* __restrict__ w2, const float* __restrict__ b2,
    float* __restrict__ out, int N, int relu_flag)
{
    __shared__ float s_w1[64 * 64];
    __shared__ float s_w2[64 * 64];
    __shared__ float s_x[4][64];
    __shared__ float s_y1[4][64];

    int tid = threadIdx.x;
    for (int i = tid; i < 64 * 64; i += 256) {
        s_w1[i] = w1[i];
        s_w2[i] = w2[i];
    }
    __syncthreads();

    int local = tid >> 6;
    int c     = tid & 63;
    float bb1 = b1[c];
    float bb2 = b2[c];

    long stride = (long)gridDim.x * 4;
    for (long base = (long)blockIdx.x * 4; base < N; base += stride) {
        long node = base + local;
        float hval = 0.f;
        if (node < N) {
            hval = h[node * HD + c];
            s_x[local][c] = scat[node * HD + c] + hval;
        }
        __syncthreads();
        if (node < N) {
            float acc = bb1;
            #pragma unroll
            for (int k = 0; k < 64; ++k)
                acc = fmaf(s_x[local][k], s_w1[k * 64 + c], acc);
            s_y1[local][c] = fmaxf(acc, 0.f);
        }
        __syncthreads();
        if (node < N) {
            float acc = bb2;
            #pragma unroll
            for (int k = 0; k < 64; ++k)
                acc = fmaf(s_y1[local][k], s_w2[k * 64 + c], acc);
            if (relu_flag) acc = fmaxf(acc, 0.f);
            out[node * HD + c] = acc + hval;
        }
        __syncthreads();
    }
}

// ---------------------------------------------------------------------------
extern "C" void kernel_launch(void* const* d_in, const int* in_sizes, int n_in,
                              void* d_out, int out_size, void* d_ws, size_t ws_size,
                              hipStream_t stream)
{
    const int*   z    = (const int*)  d_in[0];
    const int*   ei   = (const int*)  d_in[1];
    const float* ea   = (const float*)d_in[2];
    const float* t    = (const float*)d_in[3];
    const float* emb  = (const float*)d_in[4];
    const float* rw1  = (const float*)d_in[5];
    const float* rb1  = (const float*)d_in[6];
    const float* rw2  = (const float*)d_in[7];
    const float* rb2  = (const float*)d_in[8];
    const float* cw1  = (const float*)d_in[9];
    const float* cb1  = (const float*)d_in[10];
    const float* cw2  = (const float*)d_in[11];
    const float* cb2  = (const float*)d_in[12];

    int  N = in_sizes[0];
    long E = (long)in_sizes[1] / 2;
    const int* src = ei;        // edge_index[0]
    const int* dst = ei + E;    // edge_index[1]

    float* out  = (float*)d_out;
    float* bufA = (float*)d_ws;              // N*HD floats
    float* agg  = bufA + (long)N * HD;       // N*HD floats

    long nodes_elems = (long)N * HD;

    // h0 = init MLP
    node_init_kernel<<<1024, 256, 0, stream>>>(z, t, emb, rw1, rb1, rw2, rb2,
                                               bufA, N);

    float* hcur = bufA;
    for (int li = 0; li < 3; ++li) {
        float* hout = (li == 1) ? bufA : out;  // d_out, bufA, d_out
        zero_kernel<<<1024, 256, 0, stream>>>((float4*)agg, nodes_elems / 4);
        scatter_kernel<<<8192, 256, 0, stream>>>(src, dst, hcur, ea, agg, E);
        node_update_kernel<<<1024, 256, 0, stream>>>(
            agg, hcur,
            cw1 + (long)li * HD * HD, cb1 + (long)li * HD,
            cw2 + (long)li * HD * HD, cb2 + (long)li * HD,
            hout, N, (li < 2) ? 1 : 0);
        hcur = hout;
    }
}

// Round 2
// 1626.687 us; speedup vs baseline: 3.0134x; 3.0134x over previous
//
#include <hip/hip_runtime.h>

#define HD 64  // hidden dim

// ---------------------------------------------------------------------------
// zero-fill ints
// ---------------------------------------------------------------------------
__global__ void __launch_bounds__(256) zero_int_kernel(int* p, long n) {
    long i = blockIdx.x * (long)blockDim.x + threadIdx.x;
    long stride = (long)gridDim.x * blockDim.x;
    for (; i < n; i += stride) p[i] = 0;
}

// ---------------------------------------------------------------------------
// histogram of dst into cnt
// ---------------------------------------------------------------------------
__global__ void __launch_bounds__(256) hist_kernel(const int* __restrict__ dst,
                                                   int* __restrict__ cnt, long E) {
    long i = blockIdx.x * (long)blockDim.x + threadIdx.x;
    long stride = (long)gridDim.x * blockDim.x;
    for (; i < E; i += stride) atomicAdd(&cnt[dst[i]], 1);
}

// ---------------------------------------------------------------------------
// single-block exclusive scan of cnt[0..N) -> offs[0..N], and cnt becomes the
// running cursor (cnt[i] = offs[i]) for the fill pass.
// ---------------------------------------------------------------------------
__global__ void __launch_bounds__(1024) scan_kernel(int* __restrict__ cnt,
                                                    int* __restrict__ offs, int N) {
    __shared__ int s_sum[1024];
    int tid = threadIdx.x;
    int chunk = (N + 1023) / 1024;
    int begin = tid * chunk;
    int end = begin + chunk; if (end > N) end = N;
    int local = 0;
    for (int i = begin; i < end; ++i) local += cnt[i];
    s_sum[tid] = local;
    __syncthreads();
    // inclusive Hillis-Steele scan over 1024 thread sums
    for (int off = 1; off < 1024; off <<= 1) {
        int add = (tid >= off) ? s_sum[tid - off] : 0;
        __syncthreads();
        s_sum[tid] += add;
        __syncthreads();
    }
    int run = (tid == 0) ? 0 : s_sum[tid - 1];  // exclusive prefix for my chunk
    for (int i = begin; i < end; ++i) {
        int c = cnt[i];
        offs[i] = run;
        cnt[i]  = run;   // cursor init
        run += c;
    }
    if (tid == 1023) offs[N] = run;  // == E
}

// ---------------------------------------------------------------------------
// fill permutation: for each edge, place its id and src into CSR slot
// ---------------------------------------------------------------------------
__global__ void __launch_bounds__(256) fill_kernel(const int* __restrict__ src,
                                                   const int* __restrict__ dst,
                                                   int* __restrict__ cursor,
                                                   int* __restrict__ perm,
                                                   int* __restrict__ sp, long E) {
    long i = blockIdx.x * (long)blockDim.x + threadIdx.x;
    long stride = (long)gridDim.x * blockDim.x;
    for (; i < E; i += stride) {
        int d = dst[i];
        int p = atomicAdd(&cursor[d], 1);
        perm[p] = (int)i;
        sp[p]   = src[i];
    }
}

// ---------------------------------------------------------------------------
// node init: h = relu([emb[z], t] @ rw1 + rb1) @ rw2 + rb2
// block = 256 threads = 4 nodes x 64 channels, weights in LDS
// ---------------------------------------------------------------------------
__global__ void __launch_bounds__(256) node_init_kernel(
    const int* __restrict__ z, const float* __restrict__ t,
    const float* __restrict__ emb,
    const float* __restrict__ rw1, const float* __restrict__ rb1,
    const float* __restrict__ rw2, const float* __restrict__ rb2,
    float* __restrict__ h, int N)
{
    __shared__ float s_w1[65 * 64];
    __shared__ float s_w2[64 * 64];
    __shared__ float s_x[4][65];
    __shared__ float s_y1[4][64];

    int tid = threadIdx.x;
    for (int i = tid; i < 65 * 64; i += 256) s_w1[i] = rw1[i];
    for (int i = tid; i < 64 * 64; i += 256) s_w2[i] = rw2[i];
    __syncthreads();

    int local = tid >> 6;
    int c     = tid & 63;
    float b1 = rb1[c];
    float b2 = rb2[c];

    long stride = (long)gridDim.x * 4;
    for (long base = (long)blockIdx.x * 4; base < N; base += stride) {
        long node = base + local;
        if (node < N) {
            s_x[local][c] = emb[(long)z[node] * HD + c];
            if (c == 0) s_x[local][64] = t[node];
        }
        __syncthreads();
        if (node < N) {
            float acc = b1;
            #pragma unroll
            for (int k = 0; k < 65; ++k)
                acc = fmaf(s_x[local][k], s_w1[k * 64 + c], acc);
            s_y1[local][c] = fmaxf(acc, 0.f);
        }
        __syncthreads();
        if (node < N) {
            float acc = b2;
            #pragma unroll
            for (int k = 0; k < 64; ++k)
                acc = fmaf(s_y1[local][k], s_w2[k * 64 + c], acc);
            h[node * HD + c] = acc;
        }
        __syncthreads();
    }
}

// ---------------------------------------------------------------------------
// fused layer: per node n (one wave each):
//   agg = h[n] + sum_{j in CSR[n]} relu(h[sp[j]] + ea[perm[j]])
//   y = relu(agg@w1+b1)@w2+b2; if relu_flag y=relu(y); out = y + h[n]
// block = 256 = 4 waves = 4 nodes per grid-stride step; weights in LDS
// ---------------------------------------------------------------------------
__global__ void __launch_bounds__(256) layer_kernel(
    const int* __restrict__ offs, const int* __restrict__ perm,
    const int* __restrict__ sp,
    const float* __restrict__ h, const float* __restrict__ ea,
    const float* __restrict__ w1, const float* __restrict__ b1,
    const float* __restrict__ w2, const float* __restrict__ b2,
    float* __restrict__ out, int N, int relu_flag)
{
    __shared__ float s_w1[64 * 64];
    __shared__ float s_w2[64 * 64];
    __shared__ float s_x[4][64];
    __shared__ float s_y1[4][64];

    int tid = threadIdx.x;
    for (int i = tid; i < 64 * 64; i += 256) {
        s_w1[i] = w1[i];
        s_w2[i] = w2[i];
    }
    __syncthreads();

    int wv = tid >> 6;
    int c  = tid & 63;
    float bb1 = b1[c];
    float bb2 = b2[c];

    long stride = (long)gridDim.x * 4;
    for (long base = (long)blockIdx.x * 4; base < N; base += stride) {
        long node = base + wv;
        float hval = 0.f;
        if (node < N) {
            hval = h[node * HD + c];
            float acc = hval;
            int jb = offs[node], je = offs[node + 1];
            int j = jb;
            for (; j + 3 < je; j += 4) {
                int e0 = perm[j],     s0 = sp[j];
                int e1 = perm[j + 1], s1 = sp[j + 1];
                int e2 = perm[j + 2], s2 = sp[j + 2];
                int e3 = perm[j + 3], s3 = sp[j + 3];
                float m0 = h[(long)s0 * HD + c] + ea[(long)e0 * HD + c];
                float m1 = h[(long)s1 * HD + c] + ea[(long)e1 * HD + c];
                float m2 = h[(long)s2 * HD + c] + ea[(long)e2 * HD + c];
                float m3 = h[(long)s3 * HD + c] + ea[(long)e3 * HD + c];
                acc += fmaxf(m0, 0.f) + fmaxf(m1, 0.f)
                     + fmaxf(m2, 0.f) + fmaxf(m3, 0.f);
            }
            for (; j < je; ++j) {
                int e0 = perm[j], s0 = sp[j];
                acc += fmaxf(h[(long)s0 * HD + c] + ea[(long)e0 * HD + c], 0.f);
            }
            s_x[wv][c] = acc;
        }
        __syncthreads();
        if (node < N) {
            float a1 = bb1;
            #pragma unroll
            for (int k = 0; k < 64; ++k)
                a1 = fmaf(s_x[wv][k], s_w1[k * 64 + c], a1);
            s_y1[wv][c] = fmaxf(a1, 0.f);
        }
        __syncthreads();
        if (node < N) {
            float a2 = bb2;
            #pragma unroll
            for (int k = 0; k < 64; ++k)
                a2 = fmaf(s_y1[wv][k], s_w2[k * 64 + c], a2);
            if (relu_flag) a2 = fmaxf(a2, 0.f);
            out[node * HD + c] = a2 + hval;
        }
        __syncthreads();
    }
}

// ---------------------------------------------------------------------------
extern "C" void kernel_launch(void* const* d_in, const int* in_sizes, int n_in,
                              void* d_out, int out_size, void* d_ws, size_t ws_size,
                              hipStream_t stream)
{
    const int*   z    = (const int*)  d_in[0];
    const int*   ei   = (const int*)  d_in[1];
    const float* ea   = (const float*)d_in[2];
    const float* t    = (const float*)d_in[3];
    const float* emb  = (const float*)d_in[4];
    const float* rw1  = (const float*)d_in[5];
    const float* rb1  = (const float*)d_in[6];
    const float* rw2  = (const float*)d_in[7];
    const float* rb2  = (const float*)d_in[8];
    const float* cw1  = (const float*)d_in[9];
    const float* cb1  = (const float*)d_in[10];
    const float* cw2  = (const float*)d_in[11];
    const float* cb2  = (const float*)d_in[12];

    int  N = in_sizes[0];
    long E = (long)in_sizes[1] / 2;
    const int* src = ei;        // edge_index[0]
    const int* dst = ei + E;    // edge_index[1]

    float* out  = (float*)d_out;

    // workspace layout
    float* bufA   = (float*)d_ws;                 // N*HD floats (25.6 MB)
    int*   offs   = (int*)(bufA + (long)N * HD);  // N+1 ints
    int*   cursor = offs + (N + 1);               // N ints
    int*   perm   = cursor + N;                   // E ints
    int*   sp     = perm + E;                     // E ints

    // --- build CSR-by-dst index ---
    zero_int_kernel<<<256, 256, 0, stream>>>(cursor, N);
    hist_kernel<<<4096, 256, 0, stream>>>(dst, cursor, E);
    scan_kernel<<<1, 1024, 0, stream>>>(cursor, offs, N);
    fill_kernel<<<4096, 256, 0, stream>>>(src, dst, cursor, perm, sp, E);

    // --- h0 = init MLP ---
    node_init_kernel<<<1024, 256, 0, stream>>>(z, t, emb, rw1, rb1, rw2, rb2,
                                               bufA, N);

    // --- 3 GINE layers, ping-pong bufA <-> d_out ---
    float* hcur = bufA;
    for (int li = 0; li < 3; ++li) {
        float* hout = (li == 1) ? bufA : out;  // d_out, bufA, d_out
        layer_kernel<<<1024, 256, 0, stream>>>(
            offs, perm, sp, hcur, ea,
            cw1 + (long)li * HD * HD, cb1 + (long)li * HD,
            cw2 + (long)li * HD * HD, cb2 + (long)li * HD,
            hout, N, (li < 2) ? 1 : 0);
        hcur = hout;
    }
}

// Round 3
// 1126.850 us; speedup vs baseline: 4.3500x; 1.4436x over previous
//
#include <hip/hip_runtime.h>

#define HD 64  // hidden dim

// ---------------------------------------------------------------------------
// zero-fill ints
// ---------------------------------------------------------------------------
__global__ void __launch_bounds__(256) zero_int_kernel(int* p, long n) {
    long i = blockIdx.x * (long)blockDim.x + threadIdx.x;
    long stride = (long)gridDim.x * blockDim.x;
    for (; i < n; i += stride) p[i] = 0;
}

// ---------------------------------------------------------------------------
// histogram of dst into cnt
// ---------------------------------------------------------------------------
__global__ void __launch_bounds__(256) hist_kernel(const int* __restrict__ dst,
                                                   int* __restrict__ cnt, long E) {
    long i = blockIdx.x * (long)blockDim.x + threadIdx.x;
    long stride = (long)gridDim.x * blockDim.x;
    for (; i < E; i += stride) atomicAdd(&cnt[dst[i]], 1);
}

// ---------------------------------------------------------------------------
// scan stage 1: per-256-chunk sums
// ---------------------------------------------------------------------------
__global__ void __launch_bounds__(256) blocksum_kernel(const int* __restrict__ cnt,
                                                       int* __restrict__ bsum, int N) {
    int i = blockIdx.x * 256 + threadIdx.x;
    int v = (i < N) ? cnt[i] : 0;
    #pragma unroll
    for (int off = 32; off; off >>= 1) v += __shfl_down(v, off, 64);
    __shared__ int s[4];
    if ((threadIdx.x & 63) == 0) s[threadIdx.x >> 6] = v;
    __syncthreads();
    if (threadIdx.x == 0) bsum[blockIdx.x] = s[0] + s[1] + s[2] + s[3];
}

// ---------------------------------------------------------------------------
// scan stage 2: single block scans the (<=512) chunk sums -> exclusive bpre
// ---------------------------------------------------------------------------
__global__ void __launch_bounds__(512) scan2_kernel(const int* __restrict__ bsum,
                                                    int* __restrict__ bpre,
                                                    int* __restrict__ offs,
                                                    int nb, int N, int E) {
    __shared__ int s[512];
    int tid = threadIdx.x;
    int v = (tid < nb) ? bsum[tid] : 0;
    s[tid] = v;
    __syncthreads();
    for (int off = 1; off < 512; off <<= 1) {
        int add = (tid >= off) ? s[tid - off] : 0;
        __syncthreads();
        s[tid] += add;
        __syncthreads();
    }
    if (tid < nb) bpre[tid] = s[tid] - v;  // exclusive
    if (tid == 0) offs[N] = E;
}

// ---------------------------------------------------------------------------
// scan stage 3: per-chunk exclusive scan + chunk prefix -> offs, cursor
// ---------------------------------------------------------------------------
__global__ void __launch_bounds__(256) scan3_kernel(const int* __restrict__ cnt,
                                                    const int* __restrict__ bpre,
                                                    int* __restrict__ offs,
                                                    int* __restrict__ cursor, int N) {
    __shared__ int s[256];
    int tid = threadIdx.x;
    int i = blockIdx.x * 256 + tid;
    int v = (i < N) ? cnt[i] : 0;
    s[tid] = v;
    __syncthreads();
    for (int off = 1; off < 256; off <<= 1) {
        int add = (tid >= off) ? s[tid - off] : 0;
        __syncthreads();
        s[tid] += add;
        __syncthreads();
    }
    if (i < N) {
        int excl = s[tid] - v + bpre[blockIdx.x];
        offs[i] = excl;
        cursor[i] = excl;
    }
}

// ---------------------------------------------------------------------------
// fill permutation: for each edge, place its id and src into CSR slot
// ---------------------------------------------------------------------------
__global__ void __launch_bounds__(256) fill_kernel(const int* __restrict__ src,
                                                   const int* __restrict__ dst,
                                                   int* __restrict__ cursor,
                                                   int* __restrict__ perm,
                                                   int* __restrict__ sp, long E) {
    long i = blockIdx.x * (long)blockDim.x + threadIdx.x;
    long stride = (long)gridDim.x * blockDim.x;
    for (; i < E; i += stride) {
        int d = dst[i];
        int p = atomicAdd(&cursor[d], 1);
        perm[p] = (int)i;
        sp[p]   = src[i];
    }
}

// ---------------------------------------------------------------------------
// node init: h = relu([emb[z], t] @ rw1 + rb1) @ rw2 + rb2
// block = 512 = 8 waves, one node per wave per step, no inner barriers
// (per-wave-private LDS slices; in-wave LDS ordering via compiler waitcnt)
// ---------------------------------------------------------------------------
__global__ void __launch_bounds__(512, 6) node_init_kernel(
    const int* __restrict__ z, const float* __restrict__ t,
    const float* __restrict__ emb,
    const float* __restrict__ rw1, const float* __restrict__ rb1,
    const float* __restrict__ rw2, const float* __restrict__ rb2,
    float* __restrict__ h, int N)
{
    __shared__ float s_w1[65 * 64];
    __shared__ float s_w2[64 * 64];
    __shared__ float s_x[8][66];
    __shared__ float s_y1[8][64];

    int tid = threadIdx.x;
    for (int i = tid; i < 65 * 64; i += 512) s_w1[i] = rw1[i];
    for (int i = tid; i < 64 * 64; i += 512) s_w2[i] = rw2[i];
    __syncthreads();

    int wv = tid >> 6;   // 0..7
    int c  = tid & 63;
    float b1 = rb1[c];
    float b2 = rb2[c];

    long stride = (long)gridDim.x * 8;
    for (long base = (long)blockIdx.x * 8; base < N; base += stride) {
        long node = base + wv;
        if (node >= N) continue;
        s_x[wv][c] = emb[(long)z[node] * HD + c];
        if (c == 0) s_x[wv][64] = t[node];
        float acc = b1;
        #pragma unroll
        for (int k = 0; k < 65; ++k)
            acc = fmaf(s_x[wv][k], s_w1[k * 64 + c], acc);
        s_y1[wv][c] = fmaxf(acc, 0.f);
        float acc2 = b2;
        #pragma unroll
        for (int k = 0; k < 64; ++k)
            acc2 = fmaf(s_y1[wv][k], s_w2[k * 64 + c], acc2);
        h[node * HD + c] = acc2;
    }
}

// ---------------------------------------------------------------------------
// fused layer. One wave per node. Aggregation lanes: 4 edges x 16 lanes x
// float4 (one dwordx4 instruction = 1KB = 4 full edge rows). Index loads
// software-pipelined one iteration ahead. Cross-lane shfl_xor reduction.
// MLP per-wave with weights in LDS; NO block barriers in the node loop.
// ---------------------------------------------------------------------------
__global__ void __launch_bounds__(512, 6) layer_kernel(
    const int* __restrict__ offs, const int* __restrict__ perm,
    const int* __restrict__ sp,
    const float* __restrict__ h, const float* __restrict__ ea,
    const float* __restrict__ w1, const float* __restrict__ b1,
    const float* __restrict__ w2, const float* __restrict__ b2,
    float* __restrict__ out, int N, int relu_flag)
{
    __shared__ float s_w1[64 * 64];
    __shared__ float s_w2[64 * 64];
    __shared__ float s_x[8][64];
    __shared__ float s_y1[8][64];

    int tid = threadIdx.x;
    for (int i = tid; i < 64 * 64; i += 512) {
        s_w1[i] = w1[i];
        s_w2[i] = w2[i];
    }
    __syncthreads();

    int wv   = tid >> 6;        // wave in block: 0..7
    int lane = tid & 63;
    int c    = lane;            // channel (MLP phase)
    int eg   = lane >> 4;       // edge group 0..3
    int cq   = (lane & 15) * 4; // channel-quad base (agg phase)
    float bb1 = b1[c];
    float bb2 = b2[c];

    long stride = (long)gridDim.x * 8;
    for (long base = (long)blockIdx.x * 8; base < N; base += stride) {
        long node = base + wv;
        if (node >= N) continue;

        int jb = offs[node], je = offs[node + 1];
        float hval = h[node * HD + c];      // residual + self term

        float4 acc; acc.x = acc.y = acc.z = acc.w = 0.f;
        int j = jb + eg;
        int e = 0, s = 0;
        if (j < je) { e = perm[j]; s = sp[j]; }
        while (j < je) {
            const float4 av = *(const float4*)(ea + (long)e * HD + cq);
            const float4 hv = *(const float4*)(h  + (long)s * HD + cq);
            int jn = j + 4;
            int en = 0, sn = 0;
            if (jn < je) { en = perm[jn]; sn = sp[jn]; }   // prefetch next
            acc.x += fmaxf(av.x + hv.x, 0.f);
            acc.y += fmaxf(av.y + hv.y, 0.f);
            acc.z += fmaxf(av.z + hv.z, 0.f);
            acc.w += fmaxf(av.w + hv.w, 0.f);
            j = jn; e = en; s = sn;
        }
        // reduce the 4 edge groups (lanes l, l^16, l^32, l^48 share cq)
        #pragma unroll
        for (int m = 16; m <= 32; m <<= 1) {
            acc.x += __shfl_xor(acc.x, m, 64);
            acc.y += __shfl_xor(acc.y, m, 64);
            acc.z += __shfl_xor(acc.z, m, 64);
            acc.w += __shfl_xor(acc.w, m, 64);
        }
        if (lane < 16) *(float4*)&s_x[wv][cq] = acc;
        // add self term (agg = sum + h[n]); in-wave LDS ordering via waitcnt
        s_x[wv][c] += hval;

        float a1 = bb1;
        #pragma unroll
        for (int k = 0; k < 64; ++k)
            a1 = fmaf(s_x[wv][k], s_w1[k * 64 + c], a1);
        s_y1[wv][c] = fmaxf(a1, 0.f);

        float a2 = bb2;
        #pragma unroll
        for (int k = 0; k < 64; ++k)
            a2 = fmaf(s_y1[wv][k], s_w2[k * 64 + c], a2);
        if (relu_flag) a2 = fmaxf(a2, 0.f);
        out[node * HD + c] = a2 + hval;
    }
}

// ---------------------------------------------------------------------------
extern "C" void kernel_launch(void* const* d_in, const int* in_sizes, int n_in,
                              void* d_out, int out_size, void* d_ws, size_t ws_size,
                              hipStream_t stream)
{
    const int*   z    = (const int*)  d_in[0];
    const int*   ei   = (const int*)  d_in[1];
    const float* ea   = (const float*)d_in[2];
    const float* t    = (const float*)d_in[3];
    const float* emb  = (const float*)d_in[4];
    const float* rw1  = (const float*)d_in[5];
    const float* rb1  = (const float*)d_in[6];
    const float* rw2  = (const float*)d_in[7];
    const float* rb2  = (const float*)d_in[8];
    const float* cw1  = (const float*)d_in[9];
    const float* cb1  = (const float*)d_in[10];
    const float* cw2  = (const float*)d_in[11];
    const float* cb2  = (const float*)d_in[12];

    int  N = in_sizes[0];
    long E = (long)in_sizes[1] / 2;
    const int* src = ei;        // edge_index[0]
    const int* dst = ei + E;    // edge_index[1]

    float* out = (float*)d_out;

    // workspace layout
    float* bufA   = (float*)d_ws;                 // N*HD floats
    int*   offs   = (int*)(bufA + (long)N * HD);  // N+1
    int*   cursor = offs + (N + 1);               // N
    int*   perm   = cursor + N;                   // E
    int*   sp     = perm + E;                     // E
    int*   bsum   = sp + E;                       // nb
    int    nb     = (N + 255) / 256;
    int*   bpre   = bsum + nb;                    // nb

    // --- build CSR-by-dst index ---
    zero_int_kernel<<<256, 256, 0, stream>>>(cursor, N);
    hist_kernel<<<2048, 256, 0, stream>>>(dst, cursor, E);
    blocksum_kernel<<<nb, 256, 0, stream>>>(cursor, bsum, N);
    scan2_kernel<<<1, 512, 0, stream>>>(bsum, bpre, offs, nb, N, (int)E);
    scan3_kernel<<<nb, 256, 0, stream>>>(cursor, bpre, offs, cursor, N);
    fill_kernel<<<2048, 256, 0, stream>>>(src, dst, cursor, perm, sp, E);

    // --- h0 = init MLP ---
    node_init_kernel<<<1024, 512, 0, stream>>>(z, t, emb, rw1, rb1, rw2, rb2,
                                               bufA, N);

    // --- 3 GINE layers, ping-pong bufA <-> d_out ---
    float* hcur = bufA;
    for (int li = 0; li < 3; ++li) {
        float* hout = (li == 1) ? bufA : out;  // d_out, bufA, d_out
        layer_kernel<<<1024, 512, 0, stream>>>(
            offs, perm, sp, hcur, ea,
            cw1 + (long)li * HD * HD, cb1 + (long)li * HD,
            cw2 + (long)li * HD * HD, cb2 + (long)li * HD,
            hout, N, (li < 2) ? 1 : 0);
        hcur = hout;
    }
}